// Round 7
// baseline (501.409 us; speedup 1.0000x reference)
//
#include <hip/hip_runtime.h>
#include <hip/hip_bf16.h>
#include <cstdint>
#include <cstddef>

// Problem constants (T5 self-attention, B=2, S=2048, H=16, D=64, d_model=1024)
#define S_LEN 2048
#define NH 16
#define DKV 64
#define BATCH 2
#define DMODEL 1024
#define LOG2E 1.4426950408889634f

typedef _Float16 half_t;
typedef __attribute__((ext_vector_type(2))) __fp16 fp16x2;    // cvt_pkrtz result type
typedef __attribute__((ext_vector_type(4))) __fp16 fp16x4;
typedef __attribute__((ext_vector_type(4))) _Float16 halfx4;  // 8 B (also 16x16x16 A/B frag)
typedef __attribute__((ext_vector_type(8))) _Float16 half8;   // 16x16x32 A/B frag (4 VGPRs)
typedef __attribute__((ext_vector_type(4))) float floatx4;    // MFMA C/D frag / 16B store

// async global->LDS, 16 B per lane; LDS dest = wave-uniform base + lane*16
__device__ __forceinline__ void load_lds16(const half_t* g, half_t* l) {
  __builtin_amdgcn_global_load_lds((const __attribute__((address_space(1))) void*)g,
                                   (__attribute__((address_space(3))) void*)l, 16, 0, 0);
}

// ---------------------------------------------------------------------------
// T5 relative-position bucket — EXACT integer thresholds (ceil(8*16^(n/8))),
// verified to agree with the fp32 reference at every integer delta.
// ---------------------------------------------------------------------------
__device__ __forceinline__ int t5_bucket(int delta) {
  int base = (delta > 0) ? 16 : 0;
  int a = delta < 0 ? -delta : delta;
  int n;
  if (a < 8)       n = a;
  else if (a < 12) n = 8;
  else if (a < 16) n = 9;
  else if (a < 23) n = 10;
  else if (a < 32) n = 11;
  else if (a < 46) n = 12;
  else if (a < 64) n = 13;
  else if (a < 91) n = 14;
  else             n = 15;
  return base + n;
}

// ---------------------------------------------------------------------------
// prep: casts + weight transposes (bias moved into qkv_bias for overlap)
//   blocks [0, 4096)     : hidden fp32 -> fp16 flat cast
//   blocks [4096, 7168)  : w_qkv fp32 [1024][3072] -> fp16 [3072][1024]
//   blocks [7168, 8192)  : w_o   fp32 [1024][1024] -> fp16 [1024][1024]^T
// ---------------------------------------------------------------------------
__global__ __launch_bounds__(256) void prep_all(const float* __restrict__ hidden,
                                                const float* __restrict__ w_qkv,
                                                const float* __restrict__ w_o,
                                                half_t* __restrict__ Ah,
                                                half_t* __restrict__ Wqt,
                                                half_t* __restrict__ Wot) {
  __shared__ float smem[32 * 33];
  const int id = blockIdx.x;
  const int tid = threadIdx.x;

  if (id < 4096) {
    // ---- fp32 -> fp16 flat cast (hidden_states)
    const int i = id * 256 + tid;
    float4 v = ((const float4*)hidden)[i];
    halfx4 hv;
    hv[0] = (half_t)v.x; hv[1] = (half_t)v.y; hv[2] = (half_t)v.z; hv[3] = (half_t)v.w;
    ((halfx4*)Ah)[i] = hv;
  } else {
    // ---- fp32 [R][C] -> fp16 [C][R] transpose+cast (weights), 32x32 tile
    const float* in;
    half_t* out;
    int R, C, bx, by;
    if (id < 7168) {
      int t = id - 4096; bx = t % 96; by = t / 96;
      in = w_qkv; out = Wqt; R = 1024; C = 3072;
    } else {
      int t = id - 7168; bx = t & 31; by = t >> 5;
      in = w_o; out = Wot; R = 1024; C = 1024;
    }
    float (*t33)[33] = (float(*)[33])smem;
    const int lr = tid >> 3;
    const int lc = (tid & 7) * 4;
    const int r0 = by * 32, c0 = bx * 32;
    float4 v = *(const float4*)(in + (size_t)(r0 + lr) * C + c0 + lc);
    t33[lr][lc + 0] = v.x; t33[lr][lc + 1] = v.y;
    t33[lr][lc + 2] = v.z; t33[lr][lc + 3] = v.w;
    __syncthreads();
    halfx4 hv;
#pragma unroll
    for (int u = 0; u < 4; u++) hv[u] = (half_t)t33[lc + u][lr];
    *(halfx4*)(out + (size_t)(c0 + lr) * R + r0 + lc) = hv;
  }
}

// ---------------------------------------------------------------------------
// FUSED QKV GEMM + position_bias writer (write-BW / MFMA pipe OVERLAP):
//   blocks [0, 768)      : 128x128 GEMM tiles (dispatched FIRST -> resident
//                          immediately, ~3 blocks/CU via 32 KB LDS);
//   blocks [768, 33536)  : one position_bias row each (pure write-BW; fill
//                          the remaining wave slots, ~2 blocks/CU).
// GEMM: C[M=4096, N=3072] = Ah @ Wqt^T, BK=64, 4 waves 2x2, swapped-operand
// mfma(bf,af) -> transposed C in registers -> vectorized halfx4 stores.
// Q pre-scaled by log2e; V written directly transposed to [b,h,d,s].
// ---------------------------------------------------------------------------
__global__ __launch_bounds__(256) void qkv_bias(const half_t* __restrict__ A,
                                                const half_t* __restrict__ Bt,
                                                half_t* __restrict__ Qo,
                                                half_t* __restrict__ Ko,
                                                half_t* __restrict__ Vo,
                                                const float* __restrict__ table,
                                                float* __restrict__ bias_out) {
  __shared__ half_t Asl[8 * 1024];
  __shared__ half_t Bsl[8 * 1024];

  const int id = blockIdx.x;
  const int tid = threadIdx.x;

  if (id >= 768) {
    // ======================= position_bias row path =======================
    const int row = id - 768;             // 0..32767 = h*2048 + q
    const int h = row >> 11;
    const int q = row & (S_LEN - 1);
    float* tbf = (float*)Asl;             // reuse LDS
    if (tid < 32) tbf[tid] = table[tid * NH + h];
    __syncthreads();
    float* dst = bias_out + (size_t)row * S_LEN;
    const int k0 = tid * 4;
#pragma unroll
    for (int hf = 0; hf < 2; hf++) {
      int k = k0 + hf * 1024;
      floatx4 v;
      v[0] = tbf[t5_bucket((k + 0) - q)];
      v[1] = tbf[t5_bucket((k + 1) - q)];
      v[2] = tbf[t5_bucket((k + 2) - q)];
      v[3] = tbf[t5_bucket((k + 3) - q)];
      __builtin_nontemporal_store(v, (floatx4*)(dst + k));
    }
    return;
  }

  // ============================ GEMM tile path ============================
  const int bx = id % 24;                 // N/128 = 24
  const int by = id / 24;                 // M/128 = 32
  const int w = tid >> 6;
  const int lane = tid & 63;
  const int l15 = lane & 15;
  const int quad = lane >> 4;
  const int wm = w >> 1, wn = w & 1;
  const int m0 = by * 128;
  const int n0 = bx * 128;
  const int K = 1024;

  floatx4 acc[4][4];
#pragma unroll
  for (int i = 0; i < 4; i++)
#pragma unroll
    for (int j = 0; j < 4; j++) acc[i][j] = (floatx4){0.f, 0.f, 0.f, 0.f};

  const half_t* ga0 = A + (size_t)(m0 + (2 * w + 0) * 16 + l15) * K + quad * 8;
  const half_t* ga1 = A + (size_t)(m0 + (2 * w + 1) * 16 + l15) * K + quad * 8;
  const half_t* gb0 = Bt + (size_t)(n0 + (2 * w + 0) * 16 + l15) * K + quad * 8;
  const half_t* gb1 = Bt + (size_t)(n0 + (2 * w + 1) * 16 + l15) * K + quad * 8;
  half_t* la0 = &Asl[(2 * w + 0) * 1024];
  half_t* la1 = &Asl[(2 * w + 1) * 1024];
  half_t* lb0 = &Bsl[(2 * w + 0) * 1024];
  half_t* lb1 = &Bsl[(2 * w + 1) * 1024];

  for (int k0 = 0; k0 < K; k0 += 64) {
    __syncthreads();
    load_lds16(ga0 + k0,      la0);
    load_lds16(ga0 + k0 + 32, la0 + 512);
    load_lds16(ga1 + k0,      la1);
    load_lds16(ga1 + k0 + 32, la1 + 512);
    load_lds16(gb0 + k0,      lb0);
    load_lds16(gb0 + k0 + 32, lb0 + 512);
    load_lds16(gb1 + k0,      lb1);
    load_lds16(gb1 + k0 + 32, lb1 + 512);
    __syncthreads();

#pragma unroll
    for (int ks = 0; ks < 2; ks++) {
      half8 af[4], bf[4];
#pragma unroll
      for (int i = 0; i < 4; i++)
        af[i] = *(half8*)&Asl[(wm * 4 + i) * 1024 + ks * 512 + lane * 8];
#pragma unroll
      for (int j = 0; j < 4; j++)
        bf[j] = *(half8*)&Bsl[(wn * 4 + j) * 1024 + ks * 512 + lane * 8];
#pragma unroll
      for (int i = 0; i < 4; i++)
#pragma unroll
        for (int j = 0; j < 4; j++)
          acc[i][j] = __builtin_amdgcn_mfma_f32_16x16x32_f16(bf[j], af[i], acc[i][j], 0, 0, 0);
    }
  }

  // transposed C layout: lane holds C[row = rowbase+i*16+l15][col = colbase+j*16+quad*4+r]
  const int rowbase = m0 + wm * 64;
  const int colbase = n0 + wn * 64;
  const int which = colbase >> 10;            // 0=q,1=k,2=v (uniform per wave)
  const int h = (colbase & 1023) >> 6;        // uniform per wave
  const int b = rowbase >> 11;
  const int s0 = rowbase & (S_LEN - 1);
  if (which == 2) {
    // V: write directly transposed [b,h,d,s]; d = j*16 + quad*4 + r
    half_t* vbase = Vo + (size_t)(b * NH + h) * DKV * S_LEN;
#pragma unroll
    for (int i = 0; i < 4; i++)
#pragma unroll
      for (int j = 0; j < 4; j++)
#pragma unroll
        for (int r = 0; r < 4; r++)
          vbase[(size_t)(j * 16 + quad * 4 + r) * S_LEN + s0 + i * 16 + l15] =
              (half_t)acc[i][j][r];
  } else {
    const float scale = (which == 0) ? LOG2E : 1.0f;   // Q pre-scaled for exp2
    half_t* base = ((which == 0) ? Qo : Ko) + (size_t)(b * NH + h) * S_LEN * DKV;
#pragma unroll
    for (int i = 0; i < 4; i++)
#pragma unroll
      for (int j = 0; j < 4; j++) {
        halfx4 hv;
#pragma unroll
        for (int r = 0; r < 4; r++) hv[r] = (half_t)(acc[i][j][r] * scale);
        *(halfx4*)&base[(size_t)(s0 + i * 16 + l15) * DKV + j * 16 + quad * 4] = hv;
      }
  }
}

// ---------------------------------------------------------------------------
// fp16 MFMA GEMM (WO projection): C[M,N] = A[M,K] @ Bt[N,K]^T. 128x128 tile,
// BK=64, 4 waves 2x2, swapped-operand -> vectorized float4 stores.
// ---------------------------------------------------------------------------
__global__ __launch_bounds__(256) void hgemm_wo(const half_t* __restrict__ A,
                                                const half_t* __restrict__ Bt,
                                                float* __restrict__ C,
                                                int M, int N, int K) {
  __shared__ half_t Asl[8 * 1024];
  __shared__ half_t Bsl[8 * 1024];

  const int tid = threadIdx.x;
  const int w = tid >> 6;
  const int lane = tid & 63;
  const int l15 = lane & 15;
  const int quad = lane >> 4;
  const int wm = w >> 1, wn = w & 1;
  const int m0 = blockIdx.y * 128;
  const int n0 = blockIdx.x * 128;

  floatx4 acc[4][4];
#pragma unroll
  for (int i = 0; i < 4; i++)
#pragma unroll
    for (int j = 0; j < 4; j++) acc[i][j] = (floatx4){0.f, 0.f, 0.f, 0.f};

  const half_t* ga0 = A + (size_t)(m0 + (2 * w + 0) * 16 + l15) * K + quad * 8;
  const half_t* ga1 = A + (size_t)(m0 + (2 * w + 1) * 16 + l15) * K + quad * 8;
  const half_t* gb0 = Bt + (size_t)(n0 + (2 * w + 0) * 16 + l15) * K + quad * 8;
  const half_t* gb1 = Bt + (size_t)(n0 + (2 * w + 1) * 16 + l15) * K + quad * 8;
  half_t* la0 = &Asl[(2 * w + 0) * 1024];
  half_t* la1 = &Asl[(2 * w + 1) * 1024];
  half_t* lb0 = &Bsl[(2 * w + 0) * 1024];
  half_t* lb1 = &Bsl[(2 * w + 1) * 1024];

  for (int k0 = 0; k0 < K; k0 += 64) {
    __syncthreads();
    load_lds16(ga0 + k0,      la0);
    load_lds16(ga0 + k0 + 32, la0 + 512);
    load_lds16(ga1 + k0,      la1);
    load_lds16(ga1 + k0 + 32, la1 + 512);
    load_lds16(gb0 + k0,      lb0);
    load_lds16(gb0 + k0 + 32, lb0 + 512);
    load_lds16(gb1 + k0,      lb1);
    load_lds16(gb1 + k0 + 32, lb1 + 512);
    __syncthreads();

#pragma unroll
    for (int ks = 0; ks < 2; ks++) {
      half8 af[4], bf[4];
#pragma unroll
      for (int i = 0; i < 4; i++)
        af[i] = *(half8*)&Asl[(wm * 4 + i) * 1024 + ks * 512 + lane * 8];
#pragma unroll
      for (int j = 0; j < 4; j++)
        bf[j] = *(half8*)&Bsl[(wn * 4 + j) * 1024 + ks * 512 + lane * 8];
#pragma unroll
      for (int i = 0; i < 4; i++)
#pragma unroll
        for (int j = 0; j < 4; j++)
          acc[i][j] = __builtin_amdgcn_mfma_f32_16x16x32_f16(bf[j], af[i], acc[i][j], 0, 0, 0);
    }
  }

  const int rowbase = m0 + wm * 64;
  const int colbase = n0 + wn * 64;
#pragma unroll
  for (int i = 0; i < 4; i++)
#pragma unroll
    for (int j = 0; j < 4; j++)
      *(floatx4*)&C[(size_t)(rowbase + i * 16 + l15) * N + colbase + j * 16 + quad * 4] =
          acc[i][j];
}

// ---------------------------------------------------------------------------
// fp16 MFMA flash attention, 8 waves / 512 threads, 128 q/block (unchanged).
// ---------------------------------------------------------------------------
__global__ __launch_bounds__(512) void attn_fused(const half_t* __restrict__ Q,
                                                  const half_t* __restrict__ K,
                                                  const half_t* __restrict__ Vt,
                                                  const float* __restrict__ table,
                                                  half_t* __restrict__ X) {
  __shared__ half_t Ks[2 * 64 * 64];    // two [key][d] buffers, swizzled
  __shared__ half_t Vts[2 * 64 * 64];   // two [d][key] buffers, swizzled
  __shared__ float tb[32];
  __shared__ floatx4 badd4[352];        // 4 phase-copies x 88 float4 of
                                        // log2e*bias by (delta+168), aligned

  const int tid = threadIdx.x;
  const int w = tid >> 6;           // 0..7
  const int lane = tid & 63;
  const int l15 = lane & 15;
  const int quad = lane >> 4;
  const int bh = blockIdx.y;
  const int h = bh & (NH - 1);
  const int q0w = blockIdx.x * 128 + w * 16;

  if (tid < 32) tb[tid] = table[tid * NH + h] * LOG2E;
  __syncthreads();
  if (tid < 352) {
    const int p = tid / 88, t = tid - p * 88;
    floatx4 v;
#pragma unroll
    for (int e = 0; e < 4; e++) {
      int lin = p + 4 * t + e;
      if (lin > 343) lin = 343;
      v[e] = tb[t5_bucket(lin - 168)];
    }
    badd4[tid] = v;    // first consumer is after the loop's double barrier
  }
  const float tb_neg = tb[15], tb_pos = tb[31];   // capped-region biases (scaled)

  // Q B-fragments: B[k=quad*8+j][n=l15] = Q[q0w+l15][...]
  half8 qf[2];
#pragma unroll
  for (int ks = 0; ks < 2; ks++)
    qf[ks] = *(const half8*)(Q + ((size_t)bh * S_LEN + q0w + l15) * DKV +
                             ks * 32 + quad * 8);

  // O^T accumulators: o[nb] holds O[q=l15][d = nb*16 + quad*4 + r]
  floatx4 o[4];
#pragma unroll
  for (int nb = 0; nb < 4; nb++) o[nb] = (floatx4){0.f, 0.f, 0.f, 0.f};
  float m = -1e30f, l = 0.0f;       // l is PER-LANE PARTIAL (this quad's keys)

  // staging: 512 thr x 2x(16B K + 16B V); row jr = tid>>3, unit u = tid&7
  const int jr = tid >> 3;
  const int u = tid & 7;
  const int swu = (u ^ (jr & 7)) * 8;
  // S^T A-frag (K rows): addr = key*64 + ((ks*4+quad)^(key&7))*8, key=nb*16+l15
  const int kv_rd0 = l15 * 64 + ((0 * 4 + quad) ^ (l15 & 7)) * 8;
  const int kv_rd1 = l15 * 64 + ((1 * 4 + quad) ^ (l15 & 7)) * 8;
  // PV A-frag (Vt rows, b64): unit = kt*2 + (quad>>1), half-offset (quad&1)*4
  const int q2h = quad >> 1, q2l = (quad & 1) * 4;

  const half_t* Kg = K + ((size_t)bh * S_LEN + jr) * DKV + u * 8;
  const half_t* Vg = Vt + ((size_t)bh * DKV + jr) * S_LEN + u * 8;
  int rel = -q0w;   // kc - q0w, wave-uniform

  // T14: tile-pair 0 K/V prefetched into regs before the loop
  half8 kreg0 = *(const half8*)Kg;
  half8 kreg1 = *(const half8*)(Kg + 64 * DKV);
  half8 vreg0 = *(const half8*)Vg;
  half8 vreg1 = *(const half8*)(Vg + 64);

  for (int it = 0; it < 16; it++, rel += 128) {
    __syncthreads();                     // prev tiles' LDS reads done
    *(half8*)&Ks[jr * 64 + swu] = kreg0;
    *(half8*)&Ks[4096 + jr * 64 + swu] = kreg1;
    *(half8*)&Vts[jr * 64 + swu] = vreg0;
    *(half8*)&Vts[4096 + jr * 64 + swu] = vreg1;
    __syncthreads();
    if (it < 15) {                       // issue next pair's loads EARLY
      Kg += 128 * DKV;
      Vg += 128;
      kreg0 = *(const half8*)Kg;
      kreg1 = *(const half8*)(Kg + 64 * DKV);
      vreg0 = *(const half8*)Vg;
      vreg1 = *(const half8*)(Vg + 64);
    }

#pragma unroll
    for (int hb = 0; hb < 2; hb++) {
      const int relh = rel + hb * 64;
      const half_t* Kb = &Ks[hb * 4096];
      const half_t* Vb = &Vts[hb * 4096];

      // ---- S^T = K Q'^T (+bias in C-in for interior tiles) ----
      const bool capped = (relh >= 106 || relh <= -154);
      floatx4 s[4];
      if (capped) {
#pragma unroll
        for (int nb = 0; nb < 4; nb++) s[nb] = (floatx4){0.f, 0.f, 0.f, 0.f};
      } else {
        const int db = relh + quad * 4 - l15 + 168;   // in [9, 276]
        const int ph = db & 3;
        const int bb = db >> 2;
#pragma unroll
        for (int nb = 0; nb < 4; nb++) s[nb] = badd4[ph * 88 + bb + nb * 4];
      }
#pragma unroll
      for (int nb = 0; nb < 4; nb++) {
        s[nb] = __builtin_amdgcn_mfma_f32_16x16x32_f16(
            *(half8*)&Kb[nb * 1024 + kv_rd0], qf[0], s[nb], 0, 0, 0);
        s[nb] = __builtin_amdgcn_mfma_f32_16x16x32_f16(
            *(half8*)&Kb[nb * 1024 + kv_rd1], qf[1], s[nb], 0, 0, 0);
      }

      // ---- online softmax max (triple-nested for v_max3 fusion) ----
      float c0 = fmaxf(fmaxf(s[0][0], s[0][1]), s[0][2]);
      float c1 = fmaxf(fmaxf(s[0][3], s[1][0]), s[1][1]);
      float c2 = fmaxf(fmaxf(s[1][2], s[1][3]), s[2][0]);
      float c3 = fmaxf(fmaxf(s[2][1], s[2][2]), s[2][3]);
      float c4 = fmaxf(fmaxf(s[3][0], s[3][1]), s[3][2]);
      float cm = fmaxf(fmaxf(fmaxf(c0, c1), c2), fmaxf(fmaxf(c3, c4), s[3][3]));
      {
        int i = __builtin_amdgcn_ds_swizzle(__float_as_int(cm), 0x401F);  // xor 16
        cm = fmaxf(cm, __int_as_float(i));
        cm = fmaxf(cm, __shfl_xor(cm, 32));
      }
      // T13 exact: skip rescale when max didn't grow for any lane of the wave.
      if (!__all(cm <= m)) {
        float mn = fmaxf(m, cm);
        float al = exp2f(m - mn);
        l *= al;
#pragma unroll
        for (int nb = 0; nb < 4; nb++)
#pragma unroll
          for (int r = 0; r < 4; r++) o[nb][r] *= al;
        m = mn;
      }

      // ---- P = exp2(S + add), pack to f16 via pkrtz ----
      const float add = capped ? (((relh >= 106) ? tb_pos : tb_neg) - m) : (-m);
      float lsum = 0.0f;
      halfx4 pvb[4];   // PV B-frags: pvb[kt][j] = p(key = kt*16 + quad*4 + j)
#pragma unroll
      for (int nb = 0; nb < 4; nb++) {
        float p0 = exp2f(s[nb][0] + add);
        float p1 = exp2f(s[nb][1] + add);
        float p2 = exp2f(s[nb][2] + add);
        float p3 = exp2f(s[nb][3] + add);
        lsum += (p0 + p1) + (p2 + p3);
        fp16x2 a01 = __builtin_amdgcn_cvt_pkrtz(p0, p1);
        fp16x2 a23 = __builtin_amdgcn_cvt_pkrtz(p2, p3);
        fp16x4 a = __builtin_shufflevector(a01, a23, 0, 1, 2, 3);
        pvb[nb] = __builtin_bit_cast(halfx4, a);
      }
      l += lsum;   // per-lane partial; cross-quad reduce deferred to epilogue

      // ---- O^T += V^T P^T : 16 x mfma_16x16x16, A = Vt b64 frags ----
#pragma unroll
      for (int nb = 0; nb < 4; nb++) {
        const int vrow = (nb * 16 + l15);
        const int vsw = vrow & 7;
#pragma unroll
        for (int kt = 0; kt < 4; kt++) {
          halfx4 vf = *(halfx4*)&Vb[vrow * 64 + ((kt * 2 + q2h) ^ vsw) * 8 + q2l];
          o[nb] = __builtin_amdgcn_mfma_f32_16x16x16f16(vf, pvb[kt], o[nb], 0, 0, 0);
        }
      }
    }
  }

  // ---- epilogue: reduce l across quads, divide, write X fp16 directly ----
  {
    int i = __builtin_amdgcn_ds_swizzle(__float_as_int(l), 0x401F);   // xor 16
    l += __int_as_float(i);
    l += __shfl_xor(l, 32);
    const float inv = 1.0f / l;
    const int b = bh >> 4;
    half_t* xp = X + (size_t)(b * S_LEN + q0w + l15) * DMODEL + h * DKV;
#pragma unroll
    for (int nb = 0; nb < 4; nb++) {
      halfx4 hv;
#pragma unroll
      for (int r = 0; r < 4; r++) hv[r] = (half_t)(o[nb][r] * inv);
      *(halfx4*)(xp + nb * 16 + quad * 4) = hv;
    }
  }
}

// ---------------------------------------------------------------------------
// kernel_launch
// ws layout (halves): Ah 4M | Wqt 3M | Wot 1M | Qh 4M | Kh 4M | Vth 4M |
//   Xh 4M   (~48 MB). V written transposed by qkv_bias; bias overlapped.
// ---------------------------------------------------------------------------
extern "C" void kernel_launch(void* const* d_in, const int* in_sizes, int n_in,
                              void* d_out, int out_size, void* d_ws, size_t ws_size,
                              hipStream_t stream) {
  const float* hidden = (const float*)d_in[0];
  const float* w_qkv = (const float*)d_in[1];
  const float* w_o = (const float*)d_in[2];
  const float* table = (const float*)d_in[3];

  float* attn_out = (float*)d_out;
  float* bias_out = (float*)d_out + 4194304;

  half_t* Ah  = (half_t*)d_ws;     // hidden fp16
  half_t* Wqt = Ah + 4194304;      // [3072][1024]
  half_t* Wot = Wqt + 3145728;     // [1024][1024]
  half_t* Qh  = Wot + 1048576;     // [b,h,s,d], pre-scaled by log2e
  half_t* Kh  = Qh + 4194304;      // [b,h,s,d]
  half_t* Vth = Kh + 4194304;      // [b,h,d,s]  (written directly by qkv_bias)
  half_t* Xh  = Vth + 4194304;     // [4096][1024]

  // prep: casts + weight transposes
  prep_all<<<8192, 256, 0, stream>>>(hidden, w_qkv, w_o, Ah, Wqt, Wot);

  // QKV projection + position_bias (write-BW overlapped under MFMA)
  qkv_bias<<<768 + 32768, 256, 0, stream>>>(Ah, Wqt, Qh, Kh, Vth, table, bias_out);

  // fused fp16 MFMA flash attention -> Xh fp16
  attn_fused<<<dim3(S_LEN / 128, BATCH * NH), 512, 0, stream>>>(
      Qh, Kh, Vth, table, Xh);

  // output projection -> d_out fp32
  hgemm_wo<<<dim3(1024 / 128, 4096 / 128), 256, 0, stream>>>(
      Xh, Wot, attn_out, 4096, 1024, 1024);
}

// Round 8
// 492.780 us; speedup vs baseline: 1.0175x; 1.0175x over previous
//
#include <hip/hip_runtime.h>
#include <hip/hip_bf16.h>
#include <cstdint>
#include <cstddef>

// Problem constants (T5 self-attention, B=2, S=2048, H=16, D=64, d_model=1024)
#define S_LEN 2048
#define NH 16
#define DKV 64
#define BATCH 2
#define DMODEL 1024
#define LOG2E 1.4426950408889634f

typedef _Float16 half_t;
typedef __attribute__((ext_vector_type(2))) __fp16 fp16x2;    // cvt_pkrtz result type
typedef __attribute__((ext_vector_type(4))) __fp16 fp16x4;
typedef __attribute__((ext_vector_type(4))) _Float16 halfx4;  // 8 B (also 16x16x16 A/B frag)
typedef __attribute__((ext_vector_type(8))) _Float16 half8;   // 16x16x32 A/B frag (4 VGPRs)
typedef __attribute__((ext_vector_type(4))) float floatx4;    // MFMA C/D frag / 16B store

// async global->LDS, 16 B per lane; LDS dest = wave-uniform base + lane*16
__device__ __forceinline__ void load_lds16(const half_t* g, half_t* l) {
  __builtin_amdgcn_global_load_lds((const __attribute__((address_space(1))) void*)g,
                                   (__attribute__((address_space(3))) void*)l, 16, 0, 0);
}

// ---------------------------------------------------------------------------
// T5 relative-position bucket — EXACT integer thresholds (ceil(8*16^(n/8))),
// verified to agree with the fp32 reference at every integer delta.
// ---------------------------------------------------------------------------
__device__ __forceinline__ int t5_bucket(int delta) {
  int base = (delta > 0) ? 16 : 0;
  int a = delta < 0 ? -delta : delta;
  int n;
  if (a < 8)       n = a;
  else if (a < 12) n = 8;
  else if (a < 16) n = 9;
  else if (a < 23) n = 10;
  else if (a < 32) n = 11;
  else if (a < 46) n = 12;
  else if (a < 64) n = 13;
  else if (a < 91) n = 14;
  else             n = 15;
  return base + n;
}

// ---------------------------------------------------------------------------
// prep: casts + weight transposes (bias moved into wo_bias for overlap)
//   blocks [0, 4096)     : hidden fp32 -> fp16 flat cast
//   blocks [4096, 7168)  : w_qkv fp32 [1024][3072] -> fp16 [3072][1024]
//   blocks [7168, 8192)  : w_o   fp32 [1024][1024] -> fp16 [1024][1024]^T
// ---------------------------------------------------------------------------
__global__ __launch_bounds__(256) void prep_all(const float* __restrict__ hidden,
                                                const float* __restrict__ w_qkv,
                                                const float* __restrict__ w_o,
                                                half_t* __restrict__ Ah,
                                                half_t* __restrict__ Wqt,
                                                half_t* __restrict__ Wot) {
  __shared__ float smem[32 * 33];
  const int id = blockIdx.x;
  const int tid = threadIdx.x;

  if (id < 4096) {
    // ---- fp32 -> fp16 flat cast (hidden_states)
    const int i = id * 256 + tid;
    float4 v = ((const float4*)hidden)[i];
    halfx4 hv;
    hv[0] = (half_t)v.x; hv[1] = (half_t)v.y; hv[2] = (half_t)v.z; hv[3] = (half_t)v.w;
    ((halfx4*)Ah)[i] = hv;
  } else {
    // ---- fp32 [R][C] -> fp16 [C][R] transpose+cast (weights), 32x32 tile
    const float* in;
    half_t* out;
    int R, C, bx, by;
    if (id < 7168) {
      int t = id - 4096; bx = t % 96; by = t / 96;
      in = w_qkv; out = Wqt; R = 1024; C = 3072;
    } else {
      int t = id - 7168; bx = t & 31; by = t >> 5;
      in = w_o; out = Wot; R = 1024; C = 1024;
    }
    float (*t33)[33] = (float(*)[33])smem;
    const int lr = tid >> 3;
    const int lc = (tid & 7) * 4;
    const int r0 = by * 32, c0 = bx * 32;
    float4 v = *(const float4*)(in + (size_t)(r0 + lr) * C + c0 + lc);
    t33[lr][lc + 0] = v.x; t33[lr][lc + 1] = v.y;
    t33[lr][lc + 2] = v.z; t33[lr][lc + 3] = v.w;
    __syncthreads();
    halfx4 hv;
#pragma unroll
    for (int u = 0; u < 4; u++) hv[u] = (half_t)t33[lc + u][lr];
    *(halfx4*)(out + (size_t)(c0 + lr) * R + r0 + lc) = hv;
  }
}

// ---------------------------------------------------------------------------
// fp16 MFMA GEMM (QKV): C[M,N] = A[M,K] @ Bt[N,K]^T. 128x128 tile, BK=64,
// 256 thr (4 waves, 2x2), swapped-operand mfma(bf,af) -> transposed C in
// registers -> vectorized halfx4 stores. Q PRE-SCALED by log2(e); V written
// DIRECTLY TRANSPOSED to [b,h,d,s].  (Exact R6 structure — best verified.)
// ---------------------------------------------------------------------------
__global__ __launch_bounds__(256) void hgemm_qkv(const half_t* __restrict__ A,
                                                 const half_t* __restrict__ Bt,
                                                 half_t* __restrict__ Qo,
                                                 half_t* __restrict__ Ko,
                                                 half_t* __restrict__ Vo) {
  __shared__ half_t Asl[8 * 1024];
  __shared__ half_t Bsl[8 * 1024];

  const int tid = threadIdx.x;
  const int w = tid >> 6;
  const int lane = tid & 63;
  const int l15 = lane & 15;
  const int quad = lane >> 4;
  const int wm = w >> 1, wn = w & 1;
  const int m0 = blockIdx.y * 128;
  const int n0 = blockIdx.x * 128;
  const int K = 1024;

  floatx4 acc[4][4];
#pragma unroll
  for (int i = 0; i < 4; i++)
#pragma unroll
    for (int j = 0; j < 4; j++) acc[i][j] = (floatx4){0.f, 0.f, 0.f, 0.f};

  const half_t* ga0 = A + (size_t)(m0 + (2 * w + 0) * 16 + l15) * K + quad * 8;
  const half_t* ga1 = A + (size_t)(m0 + (2 * w + 1) * 16 + l15) * K + quad * 8;
  const half_t* gb0 = Bt + (size_t)(n0 + (2 * w + 0) * 16 + l15) * K + quad * 8;
  const half_t* gb1 = Bt + (size_t)(n0 + (2 * w + 1) * 16 + l15) * K + quad * 8;
  half_t* la0 = &Asl[(2 * w + 0) * 1024];
  half_t* la1 = &Asl[(2 * w + 1) * 1024];
  half_t* lb0 = &Bsl[(2 * w + 0) * 1024];
  half_t* lb1 = &Bsl[(2 * w + 1) * 1024];

  for (int k0 = 0; k0 < K; k0 += 64) {
    __syncthreads();
    load_lds16(ga0 + k0,      la0);
    load_lds16(ga0 + k0 + 32, la0 + 512);
    load_lds16(ga1 + k0,      la1);
    load_lds16(ga1 + k0 + 32, la1 + 512);
    load_lds16(gb0 + k0,      lb0);
    load_lds16(gb0 + k0 + 32, lb0 + 512);
    load_lds16(gb1 + k0,      lb1);
    load_lds16(gb1 + k0 + 32, lb1 + 512);
    __syncthreads();

#pragma unroll
    for (int ks = 0; ks < 2; ks++) {
      half8 af[4], bf[4];
#pragma unroll
      for (int i = 0; i < 4; i++)
        af[i] = *(half8*)&Asl[(wm * 4 + i) * 1024 + ks * 512 + lane * 8];
#pragma unroll
      for (int j = 0; j < 4; j++)
        bf[j] = *(half8*)&Bsl[(wn * 4 + j) * 1024 + ks * 512 + lane * 8];
#pragma unroll
      for (int i = 0; i < 4; i++)
#pragma unroll
        for (int j = 0; j < 4; j++)
          acc[i][j] = __builtin_amdgcn_mfma_f32_16x16x32_f16(bf[j], af[i], acc[i][j], 0, 0, 0);
    }
  }

  // transposed C layout: lane holds C[row = rowbase+i*16+l15][col = colbase+j*16+quad*4+r]
  const int rowbase = m0 + wm * 64;
  const int colbase = n0 + wn * 64;
  const int which = colbase >> 10;            // 0=q,1=k,2=v (uniform per wave)
  const int h = (colbase & 1023) >> 6;        // uniform per wave
  const int b = rowbase >> 11;
  const int s0 = rowbase & (S_LEN - 1);
  if (which == 2) {
    // V: write directly transposed [b,h,d,s]; d = j*16 + quad*4 + r
    half_t* vbase = Vo + (size_t)(b * NH + h) * DKV * S_LEN;
#pragma unroll
    for (int i = 0; i < 4; i++)
#pragma unroll
      for (int j = 0; j < 4; j++)
#pragma unroll
        for (int r = 0; r < 4; r++)
          vbase[(size_t)(j * 16 + quad * 4 + r) * S_LEN + s0 + i * 16 + l15] =
              (half_t)acc[i][j][r];
  } else {
    const float scale = (which == 0) ? LOG2E : 1.0f;   // Q pre-scaled for exp2
    half_t* base = ((which == 0) ? Qo : Ko) + (size_t)(b * NH + h) * S_LEN * DKV;
#pragma unroll
    for (int i = 0; i < 4; i++)
#pragma unroll
      for (int j = 0; j < 4; j++) {
        halfx4 hv;
#pragma unroll
        for (int r = 0; r < 4; r++) hv[r] = (half_t)(acc[i][j][r] * scale);
        *(halfx4*)&base[(size_t)(s0 + i * 16 + l15) * DKV + j * 16 + quad * 4] = hv;
      }
  }
}

// ---------------------------------------------------------------------------
// FUSED WO GEMM + position_bias writer.
// WO GEMM is exactly 256 blocks = 1 block/CU -> 3-4 resident-block slots/CU
// remain free for the pure-write-BW bias rows (unlike R7's failed QKV fusion
// where the GEMM already filled the CU). Blocks:
//   [0, 256)      : 128x128 WO GEMM tiles (M=4096, N=1024, K=1024)
//   [256, 33024)  : one position_bias row each (268 MB nontemporal write)
// ---------------------------------------------------------------------------
__global__ __launch_bounds__(256) void wo_bias(const half_t* __restrict__ A,
                                               const half_t* __restrict__ Bt,
                                               float* __restrict__ C,
                                               const float* __restrict__ table,
                                               float* __restrict__ bias_out) {
  __shared__ half_t Asl[8 * 1024];
  __shared__ half_t Bsl[8 * 1024];

  const int id = blockIdx.x;
  const int tid = threadIdx.x;

  if (id >= 256) {
    // ======================= position_bias row path =======================
    const int row = id - 256;             // 0..32767 = h*2048 + q
    const int h = row >> 11;
    const int q = row & (S_LEN - 1);
    float* tbf = (float*)Asl;             // reuse LDS
    if (tid < 32) tbf[tid] = table[tid * NH + h];
    __syncthreads();
    float* dst = bias_out + (size_t)row * S_LEN;
    const int k0 = tid * 4;
#pragma unroll
    for (int hf = 0; hf < 2; hf++) {
      int k = k0 + hf * 1024;
      floatx4 v;
      v[0] = tbf[t5_bucket((k + 0) - q)];
      v[1] = tbf[t5_bucket((k + 1) - q)];
      v[2] = tbf[t5_bucket((k + 2) - q)];
      v[3] = tbf[t5_bucket((k + 3) - q)];
      __builtin_nontemporal_store(v, (floatx4*)(dst + k));
    }
    return;
  }

  // ============================ WO GEMM tile ============================
  const int bx = id & 7;                  // N/128 = 8
  const int by = id >> 3;                 // M/128 = 32
  const int w = tid >> 6;
  const int lane = tid & 63;
  const int l15 = lane & 15;
  const int quad = lane >> 4;
  const int wm = w >> 1, wn = w & 1;
  const int m0 = by * 128;
  const int n0 = bx * 128;
  const int K = 1024, N = 1024;

  floatx4 acc[4][4];
#pragma unroll
  for (int i = 0; i < 4; i++)
#pragma unroll
    for (int j = 0; j < 4; j++) acc[i][j] = (floatx4){0.f, 0.f, 0.f, 0.f};

  const half_t* ga0 = A + (size_t)(m0 + (2 * w + 0) * 16 + l15) * K + quad * 8;
  const half_t* ga1 = A + (size_t)(m0 + (2 * w + 1) * 16 + l15) * K + quad * 8;
  const half_t* gb0 = Bt + (size_t)(n0 + (2 * w + 0) * 16 + l15) * K + quad * 8;
  const half_t* gb1 = Bt + (size_t)(n0 + (2 * w + 1) * 16 + l15) * K + quad * 8;
  half_t* la0 = &Asl[(2 * w + 0) * 1024];
  half_t* la1 = &Asl[(2 * w + 1) * 1024];
  half_t* lb0 = &Bsl[(2 * w + 0) * 1024];
  half_t* lb1 = &Bsl[(2 * w + 1) * 1024];

  for (int k0 = 0; k0 < K; k0 += 64) {
    __syncthreads();
    load_lds16(ga0 + k0,      la0);
    load_lds16(ga0 + k0 + 32, la0 + 512);
    load_lds16(ga1 + k0,      la1);
    load_lds16(ga1 + k0 + 32, la1 + 512);
    load_lds16(gb0 + k0,      lb0);
    load_lds16(gb0 + k0 + 32, lb0 + 512);
    load_lds16(gb1 + k0,      lb1);
    load_lds16(gb1 + k0 + 32, lb1 + 512);
    __syncthreads();

#pragma unroll
    for (int ks = 0; ks < 2; ks++) {
      half8 af[4], bf[4];
#pragma unroll
      for (int i = 0; i < 4; i++)
        af[i] = *(half8*)&Asl[(wm * 4 + i) * 1024 + ks * 512 + lane * 8];
#pragma unroll
      for (int j = 0; j < 4; j++)
        bf[j] = *(half8*)&Bsl[(wn * 4 + j) * 1024 + ks * 512 + lane * 8];
#pragma unroll
      for (int i = 0; i < 4; i++)
#pragma unroll
        for (int j = 0; j < 4; j++)
          acc[i][j] = __builtin_amdgcn_mfma_f32_16x16x32_f16(bf[j], af[i], acc[i][j], 0, 0, 0);
    }
  }

  const int rowbase = m0 + wm * 64;
  const int colbase = n0 + wn * 64;
#pragma unroll
  for (int i = 0; i < 4; i++)
#pragma unroll
    for (int j = 0; j < 4; j++)
      *(floatx4*)&C[(size_t)(rowbase + i * 16 + l15) * N + colbase + j * 16 + quad * 4] =
          acc[i][j];
}

// ---------------------------------------------------------------------------
// fp16 MFMA flash attention, 8 waves / 512 threads, 128 q/block (unchanged).
// ---------------------------------------------------------------------------
__global__ __launch_bounds__(512) void attn_fused(const half_t* __restrict__ Q,
                                                  const half_t* __restrict__ K,
                                                  const half_t* __restrict__ Vt,
                                                  const float* __restrict__ table,
                                                  half_t* __restrict__ X) {
  __shared__ half_t Ks[2 * 64 * 64];    // two [key][d] buffers, swizzled
  __shared__ half_t Vts[2 * 64 * 64];   // two [d][key] buffers, swizzled
  __shared__ float tb[32];
  __shared__ floatx4 badd4[352];        // 4 phase-copies x 88 float4 of
                                        // log2e*bias by (delta+168), aligned

  const int tid = threadIdx.x;
  const int w = tid >> 6;           // 0..7
  const int lane = tid & 63;
  const int l15 = lane & 15;
  const int quad = lane >> 4;
  const int bh = blockIdx.y;
  const int h = bh & (NH - 1);
  const int q0w = blockIdx.x * 128 + w * 16;

  if (tid < 32) tb[tid] = table[tid * NH + h] * LOG2E;
  __syncthreads();
  if (tid < 352) {
    const int p = tid / 88, t = tid - p * 88;
    floatx4 v;
#pragma unroll
    for (int e = 0; e < 4; e++) {
      int lin = p + 4 * t + e;
      if (lin > 343) lin = 343;
      v[e] = tb[t5_bucket(lin - 168)];
    }
    badd4[tid] = v;    // first consumer is after the loop's double barrier
  }
  const float tb_neg = tb[15], tb_pos = tb[31];   // capped-region biases (scaled)

  // Q B-fragments: B[k=quad*8+j][n=l15] = Q[q0w+l15][...]
  half8 qf[2];
#pragma unroll
  for (int ks = 0; ks < 2; ks++)
    qf[ks] = *(const half8*)(Q + ((size_t)bh * S_LEN + q0w + l15) * DKV +
                             ks * 32 + quad * 8);

  // O^T accumulators: o[nb] holds O[q=l15][d = nb*16 + quad*4 + r]
  floatx4 o[4];
#pragma unroll
  for (int nb = 0; nb < 4; nb++) o[nb] = (floatx4){0.f, 0.f, 0.f, 0.f};
  float m = -1e30f, l = 0.0f;       // l is PER-LANE PARTIAL (this quad's keys)

  // staging: 512 thr x 2x(16B K + 16B V); row jr = tid>>3, unit u = tid&7
  const int jr = tid >> 3;
  const int u = tid & 7;
  const int swu = (u ^ (jr & 7)) * 8;
  // S^T A-frag (K rows): addr = key*64 + ((ks*4+quad)^(key&7))*8, key=nb*16+l15
  const int kv_rd0 = l15 * 64 + ((0 * 4 + quad) ^ (l15 & 7)) * 8;
  const int kv_rd1 = l15 * 64 + ((1 * 4 + quad) ^ (l15 & 7)) * 8;
  // PV A-frag (Vt rows, b64): unit = kt*2 + (quad>>1), half-offset (quad&1)*4
  const int q2h = quad >> 1, q2l = (quad & 1) * 4;

  const half_t* Kg = K + ((size_t)bh * S_LEN + jr) * DKV + u * 8;
  const half_t* Vg = Vt + ((size_t)bh * DKV + jr) * S_LEN + u * 8;
  int rel = -q0w;   // kc - q0w, wave-uniform

  // T14: tile-pair 0 K/V prefetched into regs before the loop
  half8 kreg0 = *(const half8*)Kg;
  half8 kreg1 = *(const half8*)(Kg + 64 * DKV);
  half8 vreg0 = *(const half8*)Vg;
  half8 vreg1 = *(const half8*)(Vg + 64);

  for (int it = 0; it < 16; it++, rel += 128) {
    __syncthreads();                     // prev tiles' LDS reads done
    *(half8*)&Ks[jr * 64 + swu] = kreg0;
    *(half8*)&Ks[4096 + jr * 64 + swu] = kreg1;
    *(half8*)&Vts[jr * 64 + swu] = vreg0;
    *(half8*)&Vts[4096 + jr * 64 + swu] = vreg1;
    __syncthreads();
    if (it < 15) {                       // issue next pair's loads EARLY
      Kg += 128 * DKV;
      Vg += 128;
      kreg0 = *(const half8*)Kg;
      kreg1 = *(const half8*)(Kg + 64 * DKV);
      vreg0 = *(const half8*)Vg;
      vreg1 = *(const half8*)(Vg + 64);
    }

#pragma unroll
    for (int hb = 0; hb < 2; hb++) {
      const int relh = rel + hb * 64;
      const half_t* Kb = &Ks[hb * 4096];
      const half_t* Vb = &Vts[hb * 4096];

      // ---- S^T = K Q'^T (+bias in C-in for interior tiles) ----
      const bool capped = (relh >= 106 || relh <= -154);
      floatx4 s[4];
      if (capped) {
#pragma unroll
        for (int nb = 0; nb < 4; nb++) s[nb] = (floatx4){0.f, 0.f, 0.f, 0.f};
      } else {
        const int db = relh + quad * 4 - l15 + 168;   // in [9, 276]
        const int ph = db & 3;
        const int bb = db >> 2;
#pragma unroll
        for (int nb = 0; nb < 4; nb++) s[nb] = badd4[ph * 88 + bb + nb * 4];
      }
#pragma unroll
      for (int nb = 0; nb < 4; nb++) {
        s[nb] = __builtin_amdgcn_mfma_f32_16x16x32_f16(
            *(half8*)&Kb[nb * 1024 + kv_rd0], qf[0], s[nb], 0, 0, 0);
        s[nb] = __builtin_amdgcn_mfma_f32_16x16x32_f16(
            *(half8*)&Kb[nb * 1024 + kv_rd1], qf[1], s[nb], 0, 0, 0);
      }

      // ---- online softmax max (triple-nested for v_max3 fusion) ----
      float c0 = fmaxf(fmaxf(s[0][0], s[0][1]), s[0][2]);
      float c1 = fmaxf(fmaxf(s[0][3], s[1][0]), s[1][1]);
      float c2 = fmaxf(fmaxf(s[1][2], s[1][3]), s[2][0]);
      float c3 = fmaxf(fmaxf(s[2][1], s[2][2]), s[2][3]);
      float c4 = fmaxf(fmaxf(s[3][0], s[3][1]), s[3][2]);
      float cm = fmaxf(fmaxf(fmaxf(c0, c1), c2), fmaxf(fmaxf(c3, c4), s[3][3]));
      {
        int i = __builtin_amdgcn_ds_swizzle(__float_as_int(cm), 0x401F);  // xor 16
        cm = fmaxf(cm, __int_as_float(i));
        cm = fmaxf(cm, __shfl_xor(cm, 32));
      }
      // T13 exact: skip rescale when max didn't grow for any lane of the wave.
      if (!__all(cm <= m)) {
        float mn = fmaxf(m, cm);
        float al = exp2f(m - mn);
        l *= al;
#pragma unroll
        for (int nb = 0; nb < 4; nb++)
#pragma unroll
          for (int r = 0; r < 4; r++) o[nb][r] *= al;
        m = mn;
      }

      // ---- P = exp2(S + add), pack to f16 via pkrtz ----
      const float add = capped ? (((relh >= 106) ? tb_pos : tb_neg) - m) : (-m);
      float lsum = 0.0f;
      halfx4 pvb[4];   // PV B-frags: pvb[kt][j] = p(key = kt*16 + quad*4 + j)
#pragma unroll
      for (int nb = 0; nb < 4; nb++) {
        float p0 = exp2f(s[nb][0] + add);
        float p1 = exp2f(s[nb][1] + add);
        float p2 = exp2f(s[nb][2] + add);
        float p3 = exp2f(s[nb][3] + add);
        lsum += (p0 + p1) + (p2 + p3);
        fp16x2 a01 = __builtin_amdgcn_cvt_pkrtz(p0, p1);
        fp16x2 a23 = __builtin_amdgcn_cvt_pkrtz(p2, p3);
        fp16x4 a = __builtin_shufflevector(a01, a23, 0, 1, 2, 3);
        pvb[nb] = __builtin_bit_cast(halfx4, a);
      }
      l += lsum;   // per-lane partial; cross-quad reduce deferred to epilogue

      // ---- O^T += V^T P^T : 16 x mfma_16x16x16, A = Vt b64 frags ----
#pragma unroll
      for (int nb = 0; nb < 4; nb++) {
        const int vrow = (nb * 16 + l15);
        const int vsw = vrow & 7;
#pragma unroll
        for (int kt = 0; kt < 4; kt++) {
          halfx4 vf = *(halfx4*)&Vb[vrow * 64 + ((kt * 2 + q2h) ^ vsw) * 8 + q2l];
          o[nb] = __builtin_amdgcn_mfma_f32_16x16x16f16(vf, pvb[kt], o[nb], 0, 0, 0);
        }
      }
    }
  }

  // ---- epilogue: reduce l across quads, divide, write X fp16 directly ----
  {
    int i = __builtin_amdgcn_ds_swizzle(__float_as_int(l), 0x401F);   // xor 16
    l += __int_as_float(i);
    l += __shfl_xor(l, 32);
    const float inv = 1.0f / l;
    const int b = bh >> 4;
    half_t* xp = X + (size_t)(b * S_LEN + q0w + l15) * DMODEL + h * DKV;
#pragma unroll
    for (int nb = 0; nb < 4; nb++) {
      halfx4 hv;
#pragma unroll
      for (int r = 0; r < 4; r++) hv[r] = (half_t)(o[nb][r] * inv);
      *(halfx4*)(xp + nb * 16 + quad * 4) = hv;
    }
  }
}

// ---------------------------------------------------------------------------
// kernel_launch
// ws layout (halves): Ah 4M | Wqt 3M | Wot 1M | Qh 4M | Kh 4M | Vth 4M |
//   Xh 4M   (~48 MB). V written transposed by QKV GEMM; bias overlapped
//   with the WO GEMM (1 block/CU leaves slots free).
// ---------------------------------------------------------------------------
extern "C" void kernel_launch(void* const* d_in, const int* in_sizes, int n_in,
                              void* d_out, int out_size, void* d_ws, size_t ws_size,
                              hipStream_t stream) {
  const float* hidden = (const float*)d_in[0];
  const float* w_qkv = (const float*)d_in[1];
  const float* w_o = (const float*)d_in[2];
  const float* table = (const float*)d_in[3];

  float* attn_out = (float*)d_out;
  float* bias_out = (float*)d_out + 4194304;

  half_t* Ah  = (half_t*)d_ws;     // hidden fp16
  half_t* Wqt = Ah + 4194304;      // [3072][1024]
  half_t* Wot = Wqt + 3145728;     // [1024][1024]
  half_t* Qh  = Wot + 1048576;     // [b,h,s,d], pre-scaled by log2e
  half_t* Kh  = Qh + 4194304;      // [b,h,s,d]
  half_t* Vth = Kh + 4194304;      // [b,h,d,s]  (written directly by QKV GEMM)
  half_t* Xh  = Vth + 4194304;     // [4096][1024]

  // prep: casts + weight transposes
  prep_all<<<8192, 256, 0, stream>>>(hidden, w_qkv, w_o, Ah, Wqt, Wot);

  // QKV projection (fp16 MFMA; Q pre-scaled by log2e; V written transposed)
  hgemm_qkv<<<dim3(3072 / 128, 4096 / 128), 256, 0, stream>>>(
      Ah, Wqt, Qh, Kh, Vth);

  // fused fp16 MFMA flash attention -> Xh fp16
  attn_fused<<<dim3(S_LEN / 128, BATCH * NH), 512, 0, stream>>>(
      Qh, Kh, Vth, table, Xh);

  // output projection + position_bias (write-BW overlapped; WO = 1 block/CU)
  wo_bias<<<256 + 32768, 256, 0, stream>>>(Xh, Wot, attn_out, table, bias_out);
}

// Round 9
// 463.424 us; speedup vs baseline: 1.0820x; 1.0633x over previous
//
#include <hip/hip_runtime.h>
#include <hip/hip_bf16.h>
#include <cstdint>
#include <cstddef>

// Problem constants (T5 self-attention, B=2, S=2048, H=16, D=64, d_model=1024)
#define S_LEN 2048
#define NH 16
#define DKV 64
#define BATCH 2
#define DMODEL 1024
#define LOG2E 1.4426950408889634f

typedef _Float16 half_t;
typedef __attribute__((ext_vector_type(2))) __fp16 fp16x2;    // cvt_pkrtz result type
typedef __attribute__((ext_vector_type(4))) __fp16 fp16x4;
typedef __attribute__((ext_vector_type(4))) _Float16 halfx4;  // 8 B (also 16x16x16 A/B frag)
typedef __attribute__((ext_vector_type(8))) _Float16 half8;   // 16x16x32 A/B frag (4 VGPRs)
typedef __attribute__((ext_vector_type(4))) float floatx4;    // MFMA C/D frag / 16B store

// async global->LDS, 16 B per lane; LDS dest = wave-uniform base + lane*16
__device__ __forceinline__ void load_lds16(const half_t* g, half_t* l) {
  __builtin_amdgcn_global_load_lds((const __attribute__((address_space(1))) void*)g,
                                   (__attribute__((address_space(3))) void*)l, 16, 0, 0);
}

// ---------------------------------------------------------------------------
// T5 relative-position bucket — EXACT integer thresholds (ceil(8*16^(n/8))),
// verified to agree with the fp32 reference at every integer delta.
// ---------------------------------------------------------------------------
__device__ __forceinline__ int t5_bucket(int delta) {
  int base = (delta > 0) ? 16 : 0;
  int a = delta < 0 ? -delta : delta;
  int n;
  if (a < 8)       n = a;
  else if (a < 12) n = 8;
  else if (a < 16) n = 9;
  else if (a < 23) n = 10;
  else if (a < 32) n = 11;
  else if (a < 46) n = 12;
  else if (a < 64) n = 13;
  else if (a < 91) n = 14;
  else             n = 15;
  return base + n;
}

// ---------------------------------------------------------------------------
// FUSED prep (R6-verified best): ONE dispatch covering
//   blocks [0, 32768)        : position_bias rows (268 MB nontemporal write)
//   blocks [32768, 36864)    : hidden fp32 -> fp16 flat cast
//   blocks [36864, 39936)    : w_qkv fp32 [1024][3072] -> fp16 [3072][1024]
//   blocks [39936, 40960)    : w_o   fp32 [1024][1024] -> fp16 [1024][1024]^T
// (Bias co-dispatched with the tiny casts works; with GEMMs it regresses —
//  R7/R8 measured. Keep it here.)
// ---------------------------------------------------------------------------
__global__ __launch_bounds__(256) void prep_all(const float* __restrict__ hidden,
                                                const float* __restrict__ w_qkv,
                                                const float* __restrict__ w_o,
                                                const float* __restrict__ table,
                                                half_t* __restrict__ Ah,
                                                half_t* __restrict__ Wqt,
                                                half_t* __restrict__ Wot,
                                                float* __restrict__ bias_out) {
  __shared__ float smem[32 * 33];
  const int id = blockIdx.x;
  const int tid = threadIdx.x;

  if (id < 32768) {
    // ---- position_bias row: out[(h*S+q)*S + k] = table[bucket(k-q)*NH + h]
    const int h = id >> 11;
    const int q = id & (S_LEN - 1);
    if (tid < 32) smem[tid] = table[tid * NH + h];
    __syncthreads();
    float* dst = bias_out + (size_t)id * S_LEN;
    const int k0 = tid * 4;
#pragma unroll
    for (int hf = 0; hf < 2; hf++) {
      int k = k0 + hf * 1024;
      floatx4 v;
      v[0] = smem[t5_bucket((k + 0) - q)];
      v[1] = smem[t5_bucket((k + 1) - q)];
      v[2] = smem[t5_bucket((k + 2) - q)];
      v[3] = smem[t5_bucket((k + 3) - q)];
      __builtin_nontemporal_store(v, (floatx4*)(dst + k));
    }
  } else if (id < 36864) {
    // ---- fp32 -> fp16 flat cast (hidden_states)
    const int i = (id - 32768) * 256 + tid;
    float4 v = ((const float4*)hidden)[i];
    halfx4 hv;
    hv[0] = (half_t)v.x; hv[1] = (half_t)v.y; hv[2] = (half_t)v.z; hv[3] = (half_t)v.w;
    ((halfx4*)Ah)[i] = hv;
  } else {
    // ---- fp32 [R][C] -> fp16 [C][R] transpose+cast (weights), 32x32 tile
    const float* in;
    half_t* out;
    int R, C, bx, by;
    if (id < 39936) {
      int t = id - 36864; bx = t % 96; by = t / 96;
      in = w_qkv; out = Wqt; R = 1024; C = 3072;
    } else {
      int t = id - 39936; bx = t & 31; by = t >> 5;
      in = w_o; out = Wot; R = 1024; C = 1024;
    }
    float (*t33)[33] = (float(*)[33])smem;
    const int lr = tid >> 3;
    const int lc = (tid & 7) * 4;
    const int r0 = by * 32, c0 = bx * 32;
    float4 v = *(const float4*)(in + (size_t)(r0 + lr) * C + c0 + lc);
    t33[lr][lc + 0] = v.x; t33[lr][lc + 1] = v.y;
    t33[lr][lc + 2] = v.z; t33[lr][lc + 3] = v.w;
    __syncthreads();
    halfx4 hv;
#pragma unroll
    for (int u = 0; u < 4; u++) hv[u] = (half_t)t33[lc + u][lr];
    *(halfx4*)(out + (size_t)(c0 + lr) * R + r0 + lc) = hv;
  }
}

// ---------------------------------------------------------------------------
// fp16 MFMA GEMM: C[M,N] = A[M,K] @ Bt[N,K]^T. 128x128 tile, BK=64, 256 thr
// (4 waves, 2x2), swapped-operand mfma(bf,af) -> transposed C in registers ->
// vectorized stores.
// MODE 0: fp32 float4 NONTEMPORAL store to C (final output, never re-read).
// MODE 1: QKV scatter -> Q,K fp16 [b,h,s,d] (Q PRE-SCALED by log2(e));
//         V written DIRECTLY TRANSPOSED to [b,h,d,s].
// ---------------------------------------------------------------------------
template <int MODE>
__global__ __launch_bounds__(256) void hgemm128(const half_t* __restrict__ A,
                                                const half_t* __restrict__ Bt,
                                                float* __restrict__ C,
                                                half_t* __restrict__ Qo,
                                                half_t* __restrict__ Ko,
                                                half_t* __restrict__ Vo,
                                                int M, int N, int K) {
  __shared__ half_t Asl[8 * 1024];   // 8 row-blocks x (16 rows x 64 k), lane-linear panels
  __shared__ half_t Bsl[8 * 1024];

  const int tid = threadIdx.x;
  const int w = tid >> 6;
  const int lane = tid & 63;
  const int l15 = lane & 15;
  const int quad = lane >> 4;
  const int wm = w >> 1, wn = w & 1;
  const int m0 = blockIdx.y * 128;
  const int n0 = blockIdx.x * 128;

  floatx4 acc[4][4];
#pragma unroll
  for (int i = 0; i < 4; i++)
#pragma unroll
    for (int j = 0; j < 4; j++) acc[i][j] = (floatx4){0.f, 0.f, 0.f, 0.f};

  const half_t* ga0 = A + (size_t)(m0 + (2 * w + 0) * 16 + l15) * K + quad * 8;
  const half_t* ga1 = A + (size_t)(m0 + (2 * w + 1) * 16 + l15) * K + quad * 8;
  const half_t* gb0 = Bt + (size_t)(n0 + (2 * w + 0) * 16 + l15) * K + quad * 8;
  const half_t* gb1 = Bt + (size_t)(n0 + (2 * w + 1) * 16 + l15) * K + quad * 8;
  half_t* la0 = &Asl[(2 * w + 0) * 1024];
  half_t* la1 = &Asl[(2 * w + 1) * 1024];
  half_t* lb0 = &Bsl[(2 * w + 0) * 1024];
  half_t* lb1 = &Bsl[(2 * w + 1) * 1024];

  for (int k0 = 0; k0 < K; k0 += 64) {
    __syncthreads();
    load_lds16(ga0 + k0,      la0);
    load_lds16(ga0 + k0 + 32, la0 + 512);
    load_lds16(ga1 + k0,      la1);
    load_lds16(ga1 + k0 + 32, la1 + 512);
    load_lds16(gb0 + k0,      lb0);
    load_lds16(gb0 + k0 + 32, lb0 + 512);
    load_lds16(gb1 + k0,      lb1);
    load_lds16(gb1 + k0 + 32, lb1 + 512);
    __syncthreads();

#pragma unroll
    for (int ks = 0; ks < 2; ks++) {
      half8 af[4], bf[4];
#pragma unroll
      for (int i = 0; i < 4; i++)
        af[i] = *(half8*)&Asl[(wm * 4 + i) * 1024 + ks * 512 + lane * 8];
#pragma unroll
      for (int j = 0; j < 4; j++)
        bf[j] = *(half8*)&Bsl[(wn * 4 + j) * 1024 + ks * 512 + lane * 8];
#pragma unroll
      for (int i = 0; i < 4; i++)
#pragma unroll
        for (int j = 0; j < 4; j++)
          acc[i][j] = __builtin_amdgcn_mfma_f32_16x16x32_f16(bf[j], af[i], acc[i][j], 0, 0, 0);
    }
  }

  // transposed C layout: lane holds C[row = rowbase+i*16+l15][col = colbase+j*16+quad*4+r]
  const int rowbase = m0 + wm * 64;
  const int colbase = n0 + wn * 64;
  if (MODE == 0) {
#pragma unroll
    for (int i = 0; i < 4; i++)
#pragma unroll
      for (int j = 0; j < 4; j++)
        __builtin_nontemporal_store(
            acc[i][j],
            (floatx4*)&C[(size_t)(rowbase + i * 16 + l15) * N + colbase + j * 16 + quad * 4]);
  } else {
    const int which = colbase >> 10;            // 0=q,1=k,2=v (uniform per wave)
    const int h = (colbase & 1023) >> 6;        // uniform per wave
    const int b = rowbase >> 11;
    const int s0 = rowbase & (S_LEN - 1);
    if (which == 2) {
      // V: write directly transposed [b,h,d,s]; d = j*16 + quad*4 + r
      half_t* vbase = Vo + (size_t)(b * NH + h) * DKV * S_LEN;
#pragma unroll
      for (int i = 0; i < 4; i++)
#pragma unroll
        for (int j = 0; j < 4; j++)
#pragma unroll
          for (int r = 0; r < 4; r++)
            vbase[(size_t)(j * 16 + quad * 4 + r) * S_LEN + s0 + i * 16 + l15] =
                (half_t)acc[i][j][r];
    } else {
      const float scale = (which == 0) ? LOG2E : 1.0f;   // Q pre-scaled for exp2
      half_t* base = ((which == 0) ? Qo : Ko) + (size_t)(b * NH + h) * S_LEN * DKV;
#pragma unroll
      for (int i = 0; i < 4; i++)
#pragma unroll
        for (int j = 0; j < 4; j++) {
          halfx4 hv;
#pragma unroll
          for (int r = 0; r < 4; r++) hv[r] = (half_t)(acc[i][j][r] * scale);
          *(halfx4*)&base[(size_t)(s0 + i * 16 + l15) * DKV + j * 16 + quad * 4] = hv;
        }
    }
  }
}

// ---------------------------------------------------------------------------
// fp16 MFMA flash attention, 8 waves / 512 threads, 128 q/block.
// THIS ROUND: true LDS double-buffer, ONE barrier per 64-key tile.
//   Two 64-key buffer sets (Ks/Vts [2][4096]); per iteration:
//     write tile it+1 (from regs) into set^1   | overlaps
//     issue global loads for tile it+2         | with
//     compute tile it from set                 | compute
//     barrier
//   The dedicated write phase (R6: barrier-write-barrier) is eliminated;
//   barrier count unchanged (32), but ds_writes overlap MFMA issue and the
//   global loads get a full iteration to land. LDS 38 KB (same as R6).
//   Everything else (S^T dataflow, bias-in-C-in, T13 skip, pkrtz) as R6.
// ---------------------------------------------------------------------------
__global__ __launch_bounds__(512) void attn_fused(const half_t* __restrict__ Q,
                                                  const half_t* __restrict__ K,
                                                  const half_t* __restrict__ Vt,
                                                  const float* __restrict__ table,
                                                  half_t* __restrict__ X) {
  __shared__ half_t Ks[2 * 64 * 64];    // two [key][d] buffer sets, swizzled
  __shared__ half_t Vts[2 * 64 * 64];   // two [d][key] buffer sets, swizzled
  __shared__ float tb[32];
  __shared__ floatx4 badd4[352];        // 4 phase-copies x 88 float4 of
                                        // log2e*bias by (delta+168), aligned

  const int tid = threadIdx.x;
  const int w = tid >> 6;           // 0..7
  const int lane = tid & 63;
  const int l15 = lane & 15;
  const int quad = lane >> 4;
  const int bh = blockIdx.y;
  const int h = bh & (NH - 1);
  const int q0w = blockIdx.x * 128 + w * 16;

  if (tid < 32) tb[tid] = table[tid * NH + h] * LOG2E;
  __syncthreads();
  if (tid < 352) {
    const int p = tid / 88, t = tid - p * 88;
    floatx4 v;
#pragma unroll
    for (int e = 0; e < 4; e++) {
      int lin = p + 4 * t + e;
      if (lin > 343) lin = 343;
      v[e] = tb[t5_bucket(lin - 168)];
    }
    badd4[tid] = v;    // prologue barrier below covers this
  }
  const float tb_neg = tb[15], tb_pos = tb[31];   // capped-region biases (scaled)

  // Q B-fragments: B[k=quad*8+j][n=l15] = Q[q0w+l15][...]
  half8 qf[2];
#pragma unroll
  for (int ks = 0; ks < 2; ks++)
    qf[ks] = *(const half8*)(Q + ((size_t)bh * S_LEN + q0w + l15) * DKV +
                             ks * 32 + quad * 8);

  // O^T accumulators: o[nb] holds O[q=l15][d = nb*16 + quad*4 + r]
  floatx4 o[4];
#pragma unroll
  for (int nb = 0; nb < 4; nb++) o[nb] = (floatx4){0.f, 0.f, 0.f, 0.f};
  float m = -1e30f, l = 0.0f;       // l is PER-LANE PARTIAL (this quad's keys)

  // staging: 512 thr x (16B K + 16B V) per 64-key tile; jr = tid>>3, u = tid&7
  const int jr = tid >> 3;
  const int u = tid & 7;
  const int swu = (u ^ (jr & 7)) * 8;
  // S^T A-frag (K rows): addr = key*64 + ((ks*4+quad)^(key&7))*8, key=nb*16+l15
  const int kv_rd0 = l15 * 64 + ((0 * 4 + quad) ^ (l15 & 7)) * 8;
  const int kv_rd1 = l15 * 64 + ((1 * 4 + quad) ^ (l15 & 7)) * 8;
  // PV A-frag (Vt rows, b64): unit = kt*2 + (quad>>1), half-offset (quad&1)*4
  const int q2h = quad >> 1, q2l = (quad & 1) * 4;

  const half_t* Kg = K + ((size_t)bh * S_LEN + jr) * DKV + u * 8;
  const half_t* Vg = Vt + ((size_t)bh * DKV + jr) * S_LEN + u * 8;
  int rel = -q0w;   // kc - q0w, wave-uniform

  // prologue: tile 0 staged into set 0; tile 1 prefetched into regs
  {
    half8 k0 = *(const half8*)Kg;
    half8 v0 = *(const half8*)Vg;
    *(half8*)&Ks[jr * 64 + swu] = k0;
    *(half8*)&Vts[jr * 64 + swu] = v0;
  }
  Kg += 64 * DKV;
  Vg += 64;
  half8 kreg = *(const half8*)Kg;
  half8 vreg = *(const half8*)Vg;
  __syncthreads();

  for (int it = 0; it < 32; it++, rel += 64) {
    const int set = it & 1;
    // write tile it+1 into the other set (its last reader finished at it-1,
    // separated by the barrier at end of it-1)
    if (it < 31) {
      *(half8*)&Ks[(set ^ 1) * 4096 + jr * 64 + swu] = kreg;
      *(half8*)&Vts[(set ^ 1) * 4096 + jr * 64 + swu] = vreg;
    }
    // issue tile it+2 loads early; they land during this tile's compute
    if (it < 30) {
      Kg += 64 * DKV;
      Vg += 64;
      kreg = *(const half8*)Kg;
      vreg = *(const half8*)Vg;
    }

    const half_t* Kb = &Ks[set * 4096];
    const half_t* Vb = &Vts[set * 4096];

    // ---- S^T = K Q'^T (+bias in C-in for interior tiles) ----
    const bool capped = (rel >= 106 || rel <= -154);
    floatx4 s[4];
    if (capped) {
#pragma unroll
      for (int nb = 0; nb < 4; nb++) s[nb] = (floatx4){0.f, 0.f, 0.f, 0.f};
    } else {
      const int db = rel + quad * 4 - l15 + 168;   // in [9, 276]
      const int ph = db & 3;
      const int bb = db >> 2;
#pragma unroll
      for (int nb = 0; nb < 4; nb++) s[nb] = badd4[ph * 88 + bb + nb * 4];
    }
#pragma unroll
    for (int nb = 0; nb < 4; nb++) {
      s[nb] = __builtin_amdgcn_mfma_f32_16x16x32_f16(
          *(half8*)&Kb[nb * 1024 + kv_rd0], qf[0], s[nb], 0, 0, 0);
      s[nb] = __builtin_amdgcn_mfma_f32_16x16x32_f16(
          *(half8*)&Kb[nb * 1024 + kv_rd1], qf[1], s[nb], 0, 0, 0);
    }

    // ---- online softmax max (triple-nested for v_max3 fusion) ----
    float c0 = fmaxf(fmaxf(s[0][0], s[0][1]), s[0][2]);
    float c1 = fmaxf(fmaxf(s[0][3], s[1][0]), s[1][1]);
    float c2 = fmaxf(fmaxf(s[1][2], s[1][3]), s[2][0]);
    float c3 = fmaxf(fmaxf(s[2][1], s[2][2]), s[2][3]);
    float c4 = fmaxf(fmaxf(s[3][0], s[3][1]), s[3][2]);
    float cm = fmaxf(fmaxf(fmaxf(c0, c1), c2), fmaxf(fmaxf(c3, c4), s[3][3]));
    {
      int i = __builtin_amdgcn_ds_swizzle(__float_as_int(cm), 0x401F);  // xor 16
      cm = fmaxf(cm, __int_as_float(i));
      cm = fmaxf(cm, __shfl_xor(cm, 32));
    }
    // T13 exact: skip rescale when max didn't grow for any lane of the wave.
    if (!__all(cm <= m)) {
      float mn = fmaxf(m, cm);
      float al = exp2f(m - mn);
      l *= al;
#pragma unroll
      for (int nb = 0; nb < 4; nb++)
#pragma unroll
        for (int r = 0; r < 4; r++) o[nb][r] *= al;
      m = mn;
    }

    // ---- P = exp2(S + add), pack to f16 via pkrtz ----
    const float add = capped ? (((rel >= 106) ? tb_pos : tb_neg) - m) : (-m);
    float lsum = 0.0f;
    halfx4 pvb[4];   // PV B-frags: pvb[kt][j] = p(key = kt*16 + quad*4 + j)
#pragma unroll
    for (int nb = 0; nb < 4; nb++) {
      float p0 = exp2f(s[nb][0] + add);
      float p1 = exp2f(s[nb][1] + add);
      float p2 = exp2f(s[nb][2] + add);
      float p3 = exp2f(s[nb][3] + add);
      lsum += (p0 + p1) + (p2 + p3);
      fp16x2 a01 = __builtin_amdgcn_cvt_pkrtz(p0, p1);
      fp16x2 a23 = __builtin_amdgcn_cvt_pkrtz(p2, p3);
      fp16x4 a = __builtin_shufflevector(a01, a23, 0, 1, 2, 3);
      pvb[nb] = __builtin_bit_cast(halfx4, a);
    }
    l += lsum;   // per-lane partial; cross-quad reduce deferred to epilogue

    // ---- O^T += V^T P^T : 16 x mfma_16x16x16, A = Vt b64 frags ----
#pragma unroll
    for (int nb = 0; nb < 4; nb++) {
      const int vrow = (nb * 16 + l15);
      const int vsw = vrow & 7;
#pragma unroll
      for (int kt = 0; kt < 4; kt++) {
        halfx4 vf = *(halfx4*)&Vb[vrow * 64 + ((kt * 2 + q2h) ^ vsw) * 8 + q2l];
        o[nb] = __builtin_amdgcn_mfma_f32_16x16x16f16(vf, pvb[kt], o[nb], 0, 0, 0);
      }
    }

    __syncthreads();   // one barrier per tile: set roles swap next iteration
  }

  // ---- epilogue: reduce l across quads, divide, write X fp16 directly ----
  {
    int i = __builtin_amdgcn_ds_swizzle(__float_as_int(l), 0x401F);   // xor 16
    l += __int_as_float(i);
    l += __shfl_xor(l, 32);
    const float inv = 1.0f / l;
    const int b = bh >> 4;
    half_t* xp = X + (size_t)(b * S_LEN + q0w + l15) * DMODEL + h * DKV;
#pragma unroll
    for (int nb = 0; nb < 4; nb++) {
      halfx4 hv;
#pragma unroll
      for (int r = 0; r < 4; r++) hv[r] = (half_t)(o[nb][r] * inv);
      *(halfx4*)(xp + nb * 16 + quad * 4) = hv;
    }
  }
}

// ---------------------------------------------------------------------------
// kernel_launch  (R6 pipeline: prep(incl. bias) -> QKV -> attn -> WO)
// ws layout (halves): Ah 4M | Wqt 3M | Wot 1M | Qh 4M | Kh 4M | Vth 4M |
//   Xh 4M   (~48 MB). V written transposed by the QKV GEMM.
// ---------------------------------------------------------------------------
extern "C" void kernel_launch(void* const* d_in, const int* in_sizes, int n_in,
                              void* d_out, int out_size, void* d_ws, size_t ws_size,
                              hipStream_t stream) {
  const float* hidden = (const float*)d_in[0];
  const float* w_qkv = (const float*)d_in[1];
  const float* w_o = (const float*)d_in[2];
  const float* table = (const float*)d_in[3];

  float* attn_out = (float*)d_out;
  float* bias_out = (float*)d_out + 4194304;

  half_t* Ah  = (half_t*)d_ws;     // hidden fp16
  half_t* Wqt = Ah + 4194304;      // [3072][1024]
  half_t* Wot = Wqt + 3145728;     // [1024][1024]
  half_t* Qh  = Wot + 1048576;     // [b,h,s,d], pre-scaled by log2e
  half_t* Kh  = Qh + 4194304;      // [b,h,s,d]
  half_t* Vth = Kh + 4194304;      // [b,h,d,s]  (written directly by QKV GEMM)
  half_t* Xh  = Vth + 4194304;     // [4096][1024]

  // fused prep: bias rows + cast + both weight transposes (one dispatch)
  prep_all<<<40960, 256, 0, stream>>>(hidden, w_qkv, w_o, table,
                                      Ah, Wqt, Wot, bias_out);

  // QKV projection (fp16 MFMA; Q pre-scaled by log2e; V written transposed)
  hgemm128<1><<<dim3(3072 / 128, 4096 / 128), 256, 0, stream>>>(
      Ah, Wqt, nullptr, Qh, Kh, Vth, 4096, 3072, 1024);

  // fused fp16 MFMA flash attention (single-barrier dbuf) -> Xh fp16
  attn_fused<<<dim3(S_LEN / 128, BATCH * NH), 512, 0, stream>>>(
      Qh, Kh, Vth, table, Xh);

  // output projection -> d_out fp32 (nontemporal)
  hgemm128<0><<<dim3(1024 / 128, 4096 / 128), 256, 0, stream>>>(
      Xh, Wot, attn_out, nullptr, nullptr, nullptr, 4096, 1024, 1024);
}

// Round 10
// 455.493 us; speedup vs baseline: 1.1008x; 1.0174x over previous
//
#include <hip/hip_runtime.h>
#include <hip/hip_bf16.h>
#include <cstdint>
#include <cstddef>

// Problem constants (T5 self-attention, B=2, S=2048, H=16, D=64, d_model=1024)
#define S_LEN 2048
#define NH 16
#define DKV 64
#define BATCH 2
#define DMODEL 1024
#define LOG2E 1.4426950408889634f

typedef _Float16 half_t;
typedef __attribute__((ext_vector_type(2))) __fp16 fp16x2;    // cvt_pkrtz result type
typedef __attribute__((ext_vector_type(4))) __fp16 fp16x4;
typedef __attribute__((ext_vector_type(4))) _Float16 halfx4;  // 8 B (also 16x16x16 A/B frag)
typedef __attribute__((ext_vector_type(8))) _Float16 half8;   // 16x16x32 A/B frag (4 VGPRs)
typedef __attribute__((ext_vector_type(4))) float floatx4;    // MFMA C/D frag / 16B store

// async global->LDS, 16 B per lane; LDS dest = wave-uniform base + lane*16
__device__ __forceinline__ void load_lds16(const half_t* g, half_t* l) {
  __builtin_amdgcn_global_load_lds((const __attribute__((address_space(1))) void*)g,
                                   (__attribute__((address_space(3))) void*)l, 16, 0, 0);
}

// ---------------------------------------------------------------------------
// T5 relative-position bucket — EXACT integer thresholds (ceil(8*16^(n/8))),
// verified to agree with the fp32 reference at every integer delta.
// ---------------------------------------------------------------------------
__device__ __forceinline__ int t5_bucket(int delta) {
  int base = (delta > 0) ? 16 : 0;
  int a = delta < 0 ? -delta : delta;
  int n;
  if (a < 8)       n = a;
  else if (a < 12) n = 8;
  else if (a < 16) n = 9;
  else if (a < 23) n = 10;
  else if (a < 32) n = 11;
  else if (a < 46) n = 12;
  else if (a < 64) n = 13;
  else if (a < 91) n = 14;
  else             n = 15;
  return base + n;
}

// ---------------------------------------------------------------------------
// FUSED prep: ONE dispatch covering
//   blocks [0, 32768)        : position_bias rows (268 MB nontemporal write)
//   blocks [32768, 36864)    : hidden fp32 -> fp16 flat cast
//   blocks [36864, 39936)    : w_qkv fp32 [1024][3072] -> fp16 [3072][1024]
//   blocks [39936, 40960)    : w_o   fp32 [1024][1024] -> fp16 [1024][1024]^T
// (Bias co-dispatch with GEMMs regresses — R7/R8 measured. Keep it here.)
// ---------------------------------------------------------------------------
__global__ __launch_bounds__(256) void prep_all(const float* __restrict__ hidden,
                                                const float* __restrict__ w_qkv,
                                                const float* __restrict__ w_o,
                                                const float* __restrict__ table,
                                                half_t* __restrict__ Ah,
                                                half_t* __restrict__ Wqt,
                                                half_t* __restrict__ Wot,
                                                float* __restrict__ bias_out) {
  __shared__ float smem[32 * 33];
  const int id = blockIdx.x;
  const int tid = threadIdx.x;

  if (id < 32768) {
    // ---- position_bias row: out[(h*S+q)*S + k] = table[bucket(k-q)*NH + h]
    const int h = id >> 11;
    const int q = id & (S_LEN - 1);
    if (tid < 32) smem[tid] = table[tid * NH + h];
    __syncthreads();
    float* dst = bias_out + (size_t)id * S_LEN;
    const int k0 = tid * 4;
#pragma unroll
    for (int hf = 0; hf < 2; hf++) {
      int k = k0 + hf * 1024;
      floatx4 v;
      v[0] = smem[t5_bucket((k + 0) - q)];
      v[1] = smem[t5_bucket((k + 1) - q)];
      v[2] = smem[t5_bucket((k + 2) - q)];
      v[3] = smem[t5_bucket((k + 3) - q)];
      __builtin_nontemporal_store(v, (floatx4*)(dst + k));
    }
  } else if (id < 36864) {
    // ---- fp32 -> fp16 flat cast (hidden_states)
    const int i = (id - 32768) * 256 + tid;
    float4 v = ((const float4*)hidden)[i];
    halfx4 hv;
    hv[0] = (half_t)v.x; hv[1] = (half_t)v.y; hv[2] = (half_t)v.z; hv[3] = (half_t)v.w;
    ((halfx4*)Ah)[i] = hv;
  } else {
    // ---- fp32 [R][C] -> fp16 [C][R] transpose+cast (weights), 32x32 tile
    const float* in;
    half_t* out;
    int R, C, bx, by;
    if (id < 39936) {
      int t = id - 36864; bx = t % 96; by = t / 96;
      in = w_qkv; out = Wqt; R = 1024; C = 3072;
    } else {
      int t = id - 39936; bx = t & 31; by = t >> 5;
      in = w_o; out = Wot; R = 1024; C = 1024;
    }
    float (*t33)[33] = (float(*)[33])smem;
    const int lr = tid >> 3;
    const int lc = (tid & 7) * 4;
    const int r0 = by * 32, c0 = bx * 32;
    float4 v = *(const float4*)(in + (size_t)(r0 + lr) * C + c0 + lc);
    t33[lr][lc + 0] = v.x; t33[lr][lc + 1] = v.y;
    t33[lr][lc + 2] = v.z; t33[lr][lc + 3] = v.w;
    __syncthreads();
    halfx4 hv;
#pragma unroll
    for (int u = 0; u < 4; u++) hv[u] = (half_t)t33[lc + u][lr];
    *(halfx4*)(out + (size_t)(c0 + lr) * R + r0 + lc) = hv;
  }
}

// ---------------------------------------------------------------------------
// fp16 MFMA GEMM: C[M,N] = A[M,K] @ Bt[N,K]^T. 128x128 tile, BK=64, 256 thr
// (4 waves, 2x2), swapped-operand mfma(bf,af) -> transposed C in registers ->
// vectorized stores.
// MODE 0: fp32 float4 store to C.
// MODE 1: QKV scatter -> Q,K fp16 [b,h,s,d] (Q PRE-SCALED by log2(e));
//         V written DIRECTLY TRANSPOSED to [b,h,d,s].
// ---------------------------------------------------------------------------
template <int MODE>
__global__ __launch_bounds__(256) void hgemm128(const half_t* __restrict__ A,
                                                const half_t* __restrict__ Bt,
                                                float* __restrict__ C,
                                                half_t* __restrict__ Qo,
                                                half_t* __restrict__ Ko,
                                                half_t* __restrict__ Vo,
                                                int M, int N, int K) {
  __shared__ half_t Asl[8 * 1024];   // 8 row-blocks x (16 rows x 64 k), lane-linear panels
  __shared__ half_t Bsl[8 * 1024];

  const int tid = threadIdx.x;
  const int w = tid >> 6;
  const int lane = tid & 63;
  const int l15 = lane & 15;
  const int quad = lane >> 4;
  const int wm = w >> 1, wn = w & 1;
  const int m0 = blockIdx.y * 128;
  const int n0 = blockIdx.x * 128;

  floatx4 acc[4][4];
#pragma unroll
  for (int i = 0; i < 4; i++)
#pragma unroll
    for (int j = 0; j < 4; j++) acc[i][j] = (floatx4){0.f, 0.f, 0.f, 0.f};

  const half_t* ga0 = A + (size_t)(m0 + (2 * w + 0) * 16 + l15) * K + quad * 8;
  const half_t* ga1 = A + (size_t)(m0 + (2 * w + 1) * 16 + l15) * K + quad * 8;
  const half_t* gb0 = Bt + (size_t)(n0 + (2 * w + 0) * 16 + l15) * K + quad * 8;
  const half_t* gb1 = Bt + (size_t)(n0 + (2 * w + 1) * 16 + l15) * K + quad * 8;
  half_t* la0 = &Asl[(2 * w + 0) * 1024];
  half_t* la1 = &Asl[(2 * w + 1) * 1024];
  half_t* lb0 = &Bsl[(2 * w + 0) * 1024];
  half_t* lb1 = &Bsl[(2 * w + 1) * 1024];

  for (int k0 = 0; k0 < K; k0 += 64) {
    __syncthreads();
    load_lds16(ga0 + k0,      la0);
    load_lds16(ga0 + k0 + 32, la0 + 512);
    load_lds16(ga1 + k0,      la1);
    load_lds16(ga1 + k0 + 32, la1 + 512);
    load_lds16(gb0 + k0,      lb0);
    load_lds16(gb0 + k0 + 32, lb0 + 512);
    load_lds16(gb1 + k0,      lb1);
    load_lds16(gb1 + k0 + 32, lb1 + 512);
    __syncthreads();

#pragma unroll
    for (int ks = 0; ks < 2; ks++) {
      half8 af[4], bf[4];
#pragma unroll
      for (int i = 0; i < 4; i++)
        af[i] = *(half8*)&Asl[(wm * 4 + i) * 1024 + ks * 512 + lane * 8];
#pragma unroll
      for (int j = 0; j < 4; j++)
        bf[j] = *(half8*)&Bsl[(wn * 4 + j) * 1024 + ks * 512 + lane * 8];
#pragma unroll
      for (int i = 0; i < 4; i++)
#pragma unroll
        for (int j = 0; j < 4; j++)
          acc[i][j] = __builtin_amdgcn_mfma_f32_16x16x32_f16(bf[j], af[i], acc[i][j], 0, 0, 0);
    }
  }

  // transposed C layout: lane holds C[row = rowbase+i*16+l15][col = colbase+j*16+quad*4+r]
  const int rowbase = m0 + wm * 64;
  const int colbase = n0 + wn * 64;
  if (MODE == 0) {
#pragma unroll
    for (int i = 0; i < 4; i++)
#pragma unroll
      for (int j = 0; j < 4; j++)
        *(floatx4*)&C[(size_t)(rowbase + i * 16 + l15) * N + colbase + j * 16 + quad * 4] =
            acc[i][j];
  } else {
    const int which = colbase >> 10;            // 0=q,1=k,2=v (uniform per wave)
    const int h = (colbase & 1023) >> 6;        // uniform per wave
    const int b = rowbase >> 11;
    const int s0 = rowbase & (S_LEN - 1);
    if (which == 2) {
      // V: write directly transposed [b,h,d,s]; d = j*16 + quad*4 + r
      half_t* vbase = Vo + (size_t)(b * NH + h) * DKV * S_LEN;
#pragma unroll
      for (int i = 0; i < 4; i++)
#pragma unroll
        for (int j = 0; j < 4; j++)
#pragma unroll
          for (int r = 0; r < 4; r++)
            vbase[(size_t)(j * 16 + quad * 4 + r) * S_LEN + s0 + i * 16 + l15] =
                (half_t)acc[i][j][r];
    } else {
      const float scale = (which == 0) ? LOG2E : 1.0f;   // Q pre-scaled for exp2
      half_t* base = ((which == 0) ? Qo : Ko) + (size_t)(b * NH + h) * S_LEN * DKV;
#pragma unroll
      for (int i = 0; i < 4; i++)
#pragma unroll
        for (int j = 0; j < 4; j++) {
          halfx4 hv;
#pragma unroll
          for (int r = 0; r < 4; r++) hv[r] = (half_t)(acc[i][j][r] * scale);
          *(halfx4*)&base[(size_t)(s0 + i * 16 + l15) * DKV + j * 16 + quad * 4] = hv;
        }
    }
  }
}

// ---------------------------------------------------------------------------
// fp16 MFMA flash attention, 8 waves / 512 threads, 128 q/block.
//  - 128 keys staged per barrier pair (two 64-key buffers, identical layout)
//    -> 16 barrier pairs, deep T14 prefetch (loads issued right after the
//    second barrier get a full 128-key compute phase to land);
//  - bias folded into MFMA C-in via 4-phase float4-aligned table;
//  - max-reduce shaped for v_max3; P f32->f16 via v_cvt_pkrtz;
//  - T13 exact rescale skip; per-lane partial l (reduced in epilogue).
// (R9's single-barrier dbuf regressed: __syncthreads' vmcnt(0) drains the
//  prefetch at the end-of-iter barrier. This layout is the verified best.)
// ---------------------------------------------------------------------------
__global__ __launch_bounds__(512) void attn_fused(const half_t* __restrict__ Q,
                                                  const half_t* __restrict__ K,
                                                  const half_t* __restrict__ Vt,
                                                  const float* __restrict__ table,
                                                  half_t* __restrict__ X) {
  __shared__ half_t Ks[2 * 64 * 64];    // two [key][d] buffers, swizzled
  __shared__ half_t Vts[2 * 64 * 64];   // two [d][key] buffers, swizzled
  __shared__ float tb[32];
  __shared__ floatx4 badd4[352];        // 4 phase-copies x 88 float4 of
                                        // log2e*bias by (delta+168), aligned

  const int tid = threadIdx.x;
  const int w = tid >> 6;           // 0..7
  const int lane = tid & 63;
  const int l15 = lane & 15;
  const int quad = lane >> 4;
  const int bh = blockIdx.y;
  const int h = bh & (NH - 1);
  const int q0w = blockIdx.x * 128 + w * 16;

  if (tid < 32) tb[tid] = table[tid * NH + h] * LOG2E;
  __syncthreads();
  if (tid < 352) {
    const int p = tid / 88, t = tid - p * 88;
    floatx4 v;
#pragma unroll
    for (int e = 0; e < 4; e++) {
      int lin = p + 4 * t + e;
      if (lin > 343) lin = 343;
      v[e] = tb[t5_bucket(lin - 168)];
    }
    badd4[tid] = v;    // first consumer is after the loop's double barrier
  }
  const float tb_neg = tb[15], tb_pos = tb[31];   // capped-region biases (scaled)

  // Q B-fragments: B[k=quad*8+j][n=l15] = Q[q0w+l15][...]
  half8 qf[2];
#pragma unroll
  for (int ks = 0; ks < 2; ks++)
    qf[ks] = *(const half8*)(Q + ((size_t)bh * S_LEN + q0w + l15) * DKV +
                             ks * 32 + quad * 8);

  // O^T accumulators: o[nb] holds O[q=l15][d = nb*16 + quad*4 + r]
  floatx4 o[4];
#pragma unroll
  for (int nb = 0; nb < 4; nb++) o[nb] = (floatx4){0.f, 0.f, 0.f, 0.f};
  float m = -1e30f, l = 0.0f;       // l is PER-LANE PARTIAL (this quad's keys)

  // staging: 512 thr x 2x(16B K + 16B V); row jr = tid>>3, unit u = tid&7
  const int jr = tid >> 3;
  const int u = tid & 7;
  const int swu = (u ^ (jr & 7)) * 8;
  // S^T A-frag (K rows): addr = key*64 + ((ks*4+quad)^(key&7))*8, key=nb*16+l15
  const int kv_rd0 = l15 * 64 + ((0 * 4 + quad) ^ (l15 & 7)) * 8;
  const int kv_rd1 = l15 * 64 + ((1 * 4 + quad) ^ (l15 & 7)) * 8;
  // PV A-frag (Vt rows, b64): unit = kt*2 + (quad>>1), half-offset (quad&1)*4
  const int q2h = quad >> 1, q2l = (quad & 1) * 4;

  const half_t* Kg = K + ((size_t)bh * S_LEN + jr) * DKV + u * 8;
  const half_t* Vg = Vt + ((size_t)bh * DKV + jr) * S_LEN + u * 8;
  int rel = -q0w;   // kc - q0w, wave-uniform

  // T14: tile-pair 0 K/V prefetched into regs before the loop
  half8 kreg0 = *(const half8*)Kg;
  half8 kreg1 = *(const half8*)(Kg + 64 * DKV);
  half8 vreg0 = *(const half8*)Vg;
  half8 vreg1 = *(const half8*)(Vg + 64);

  for (int it = 0; it < 16; it++, rel += 128) {
    __syncthreads();                     // prev tiles' LDS reads done
    *(half8*)&Ks[jr * 64 + swu] = kreg0;
    *(half8*)&Ks[4096 + jr * 64 + swu] = kreg1;
    *(half8*)&Vts[jr * 64 + swu] = vreg0;
    *(half8*)&Vts[4096 + jr * 64 + swu] = vreg1;
    __syncthreads();
    if (it < 15) {                       // issue next pair's loads EARLY
      Kg += 128 * DKV;
      Vg += 128;
      kreg0 = *(const half8*)Kg;
      kreg1 = *(const half8*)(Kg + 64 * DKV);
      vreg0 = *(const half8*)Vg;
      vreg1 = *(const half8*)(Vg + 64);
    }

#pragma unroll
    for (int hb = 0; hb < 2; hb++) {
      const int relh = rel + hb * 64;
      const half_t* Kb = &Ks[hb * 4096];
      const half_t* Vb = &Vts[hb * 4096];

      // ---- S^T = K Q'^T (+bias in C-in for interior tiles) ----
      const bool capped = (relh >= 106 || relh <= -154);
      floatx4 s[4];
      if (capped) {
#pragma unroll
        for (int nb = 0; nb < 4; nb++) s[nb] = (floatx4){0.f, 0.f, 0.f, 0.f};
      } else {
        const int db = relh + quad * 4 - l15 + 168;   // in [9, 276]
        const int ph = db & 3;
        const int bb = db >> 2;
#pragma unroll
        for (int nb = 0; nb < 4; nb++) s[nb] = badd4[ph * 88 + bb + nb * 4];
      }
#pragma unroll
      for (int nb = 0; nb < 4; nb++) {
        s[nb] = __builtin_amdgcn_mfma_f32_16x16x32_f16(
            *(half8*)&Kb[nb * 1024 + kv_rd0], qf[0], s[nb], 0, 0, 0);
        s[nb] = __builtin_amdgcn_mfma_f32_16x16x32_f16(
            *(half8*)&Kb[nb * 1024 + kv_rd1], qf[1], s[nb], 0, 0, 0);
      }

      // ---- online softmax max (triple-nested for v_max3 fusion) ----
      float c0 = fmaxf(fmaxf(s[0][0], s[0][1]), s[0][2]);
      float c1 = fmaxf(fmaxf(s[0][3], s[1][0]), s[1][1]);
      float c2 = fmaxf(fmaxf(s[1][2], s[1][3]), s[2][0]);
      float c3 = fmaxf(fmaxf(s[2][1], s[2][2]), s[2][3]);
      float c4 = fmaxf(fmaxf(s[3][0], s[3][1]), s[3][2]);
      float cm = fmaxf(fmaxf(fmaxf(c0, c1), c2), fmaxf(fmaxf(c3, c4), s[3][3]));
      {
        int i = __builtin_amdgcn_ds_swizzle(__float_as_int(cm), 0x401F);  // xor 16
        cm = fmaxf(cm, __int_as_float(i));
        cm = fmaxf(cm, __shfl_xor(cm, 32));
      }
      // T13 exact: skip rescale when max didn't grow for any lane of the wave.
      if (!__all(cm <= m)) {
        float mn = fmaxf(m, cm);
        float al = exp2f(m - mn);
        l *= al;
#pragma unroll
        for (int nb = 0; nb < 4; nb++)
#pragma unroll
          for (int r = 0; r < 4; r++) o[nb][r] *= al;
        m = mn;
      }

      // ---- P = exp2(S + add), pack to f16 via pkrtz ----
      const float add = capped ? (((relh >= 106) ? tb_pos : tb_neg) - m) : (-m);
      float lsum = 0.0f;
      halfx4 pvb[4];   // PV B-frags: pvb[kt][j] = p(key = kt*16 + quad*4 + j)
#pragma unroll
      for (int nb = 0; nb < 4; nb++) {
        float p0 = exp2f(s[nb][0] + add);
        float p1 = exp2f(s[nb][1] + add);
        float p2 = exp2f(s[nb][2] + add);
        float p3 = exp2f(s[nb][3] + add);
        lsum += (p0 + p1) + (p2 + p3);
        fp16x2 a01 = __builtin_amdgcn_cvt_pkrtz(p0, p1);
        fp16x2 a23 = __builtin_amdgcn_cvt_pkrtz(p2, p3);
        fp16x4 a = __builtin_shufflevector(a01, a23, 0, 1, 2, 3);
        pvb[nb] = __builtin_bit_cast(halfx4, a);
      }
      l += lsum;   // per-lane partial; cross-quad reduce deferred to epilogue

      // ---- O^T += V^T P^T : 16 x mfma_16x16x16, A = Vt b64 frags ----
#pragma unroll
      for (int nb = 0; nb < 4; nb++) {
        const int vrow = (nb * 16 + l15);
        const int vsw = vrow & 7;
#pragma unroll
        for (int kt = 0; kt < 4; kt++) {
          halfx4 vf = *(halfx4*)&Vb[vrow * 64 + ((kt * 2 + q2h) ^ vsw) * 8 + q2l];
          o[nb] = __builtin_amdgcn_mfma_f32_16x16x16f16(vf, pvb[kt], o[nb], 0, 0, 0);
        }
      }
    }
  }

  // ---- epilogue: reduce l across quads, divide, write X fp16 directly ----
  {
    int i = __builtin_amdgcn_ds_swizzle(__float_as_int(l), 0x401F);   // xor 16
    l += __int_as_float(i);
    l += __shfl_xor(l, 32);
    const float inv = 1.0f / l;
    const int b = bh >> 4;
    half_t* xp = X + (size_t)(b * S_LEN + q0w + l15) * DMODEL + h * DKV;
#pragma unroll
    for (int nb = 0; nb < 4; nb++) {
      halfx4 hv;
#pragma unroll
      for (int r = 0; r < 4; r++) hv[r] = (half_t)(o[nb][r] * inv);
      *(halfx4*)(xp + nb * 16 + quad * 4) = hv;
    }
  }
}

// ---------------------------------------------------------------------------
// kernel_launch  (R6 pipeline — best verified: 457.8 µs)
// ws layout (halves): Ah 4M | Wqt 3M | Wot 1M | Qh 4M | Kh 4M | Vth 4M |
//   Xh 4M   (~48 MB). V written transposed by the QKV GEMM (no vtrans).
// ---------------------------------------------------------------------------
extern "C" void kernel_launch(void* const* d_in, const int* in_sizes, int n_in,
                              void* d_out, int out_size, void* d_ws, size_t ws_size,
                              hipStream_t stream) {
  const float* hidden = (const float*)d_in[0];
  const float* w_qkv = (const float*)d_in[1];
  const float* w_o = (const float*)d_in[2];
  const float* table = (const float*)d_in[3];

  float* attn_out = (float*)d_out;
  float* bias_out = (float*)d_out + 4194304;

  half_t* Ah  = (half_t*)d_ws;     // hidden fp16
  half_t* Wqt = Ah + 4194304;      // [3072][1024]
  half_t* Wot = Wqt + 3145728;     // [1024][1024]
  half_t* Qh  = Wot + 1048576;     // [b,h,s,d], pre-scaled by log2e
  half_t* Kh  = Qh + 4194304;      // [b,h,s,d]
  half_t* Vth = Kh + 4194304;      // [b,h,d,s]  (written directly by QKV GEMM)
  half_t* Xh  = Vth + 4194304;     // [4096][1024]

  // fused prep: bias rows + cast + both weight transposes (one dispatch)
  prep_all<<<40960, 256, 0, stream>>>(hidden, w_qkv, w_o, table,
                                      Ah, Wqt, Wot, bias_out);

  // QKV projection (fp16 MFMA; Q pre-scaled by log2e; V written transposed)
  hgemm128<1><<<dim3(3072 / 128, 4096 / 128), 256, 0, stream>>>(
      Ah, Wqt, nullptr, Qh, Kh, Vth, 4096, 3072, 1024);

  // fused fp16 MFMA flash attention -> Xh fp16
  attn_fused<<<dim3(S_LEN / 128, BATCH * NH), 512, 0, stream>>>(
      Qh, Kh, Vth, table, Xh);

  // output projection -> d_out fp32
  hgemm128<0><<<dim3(1024 / 128, 4096 / 128), 256, 0, stream>>>(
      Xh, Wot, attn_out, nullptr, nullptr, nullptr, 4096, 1024, 1024);
}